// Round 1
// baseline (363.967 us; speedup 1.0000x reference)
//
#include <hip/hip_runtime.h>

#define BB 128
#define CC 272
#define TT 1024
#define DD 270
#define KK 32
#define CKP 288          // C padded to 9*32 for the MFMA K loop
#define MP  272          // D padded to 17*16
#define NT  64           // t-tile per block
#define LDS_LD 40        // padded LDS row length in ushorts (80 B, 16B-aligned, ~conflict-free)

typedef __attribute__((ext_vector_type(8))) short s16x8;
typedef __attribute__((ext_vector_type(4))) float f32x4;
typedef __attribute__((ext_vector_type(4))) unsigned int u32x4;

__device__ __forceinline__ unsigned short f2bf(float f) {
  unsigned int u = __builtin_bit_cast(unsigned int, f);
  u += 0x7fffu + ((u >> 16) & 1u);   // round-to-nearest-even
  return (unsigned short)(u >> 16);
}

// ---------------- Kernel 1: A[d][c] in fp32 -------------------------------
// A[d,c] = sum_{k,l} z_re[d,k,l]*cos(2pi(k x_c + l y_c)) + z_im[d,k,l]*sin(...)
// cos(kx+ly) = ck*cl - sk*sl ; sin = sk*cl + ck*sl  -> 4 FMA inner loop:
//   sum_l = ck*(S_rc + S_is) + sk*(S_ic - S_rs)
__global__ __launch_bounds__(288) void phaseA_kernel(
    const float* __restrict__ loc, const float* __restrict__ z_re,
    const float* __restrict__ z_im, float* __restrict__ A) {
  const int d = blockIdx.x;
  const int c = threadIdx.x;
  if (c >= CC) return;
  const float TWO_PI = 6.28318530717958647692f;
  float x = loc[2 * c], y = loc[2 * c + 1];
  float sx, cx, sy, cyv;
  sincosf(TWO_PI * x, &sx, &cx);
  sincosf(TWO_PI * y, &sy, &cyv);
  // l-tables via rotation recurrence (error ~1e-5, negligible for softmax)
  float cl[KK], sl[KK];
  cl[0] = 1.f; sl[0] = 0.f;
#pragma unroll
  for (int l = 1; l < KK; ++l) {
    cl[l] = cl[l - 1] * cyv - sl[l - 1] * sy;
    sl[l] = sl[l - 1] * cyv + cl[l - 1] * sy;
  }
  const float* zr = z_re + (size_t)d * (KK * KK);
  const float* zi = z_im + (size_t)d * (KK * KK);
  float acc = 0.f;
  float ck = 1.f, sk = 0.f;
  for (int k = 0; k < KK; ++k) {
    float s_rc = 0.f, s_rs = 0.f, s_ic = 0.f, s_is = 0.f;
#pragma unroll
    for (int l = 0; l < KK; ++l) {
      float vr = zr[k * KK + l];   // uniform across lanes -> scalar loads
      float vi = zi[k * KK + l];
      s_rc += vr * cl[l];
      s_rs += vr * sl[l];
      s_ic += vi * cl[l];
      s_is += vi * sl[l];
    }
    acc += ck * (s_rc + s_is) + sk * (s_ic - s_rs);
    float nck = ck * cx - sk * sx;
    sk = sk * cx + ck * sx;
    ck = nck;
  }
  A[d * CC + c] = acc;
}

// ---------------- Kernel 2: row softmax -> bf16 w, zero-padded ------------
__global__ __launch_bounds__(64) void softmax_kernel(
    const float* __restrict__ A, unsigned short* __restrict__ wb) {
  const int d = blockIdx.x;   // 0..271 (rows >=270 are M-padding -> zeros)
  const int lane = threadIdx.x;
  if (d >= DD) {
#pragma unroll
    for (int j = 0; j < 5; ++j) {
      int cidx = lane + 64 * j;
      if (cidx < CKP) wb[(size_t)d * CKP + cidx] = 0;
    }
    return;
  }
  float v[5];
  float m = -3.0e38f;
#pragma unroll
  for (int j = 0; j < 5; ++j) {
    int cidx = lane + 64 * j;
    v[j] = (cidx < CC) ? A[(size_t)d * CC + cidx] : -3.0e38f;
    m = fmaxf(m, v[j]);
  }
#pragma unroll
  for (int off = 32; off >= 1; off >>= 1) m = fmaxf(m, __shfl_xor(m, off, 64));
  float s = 0.f;
#pragma unroll
  for (int j = 0; j < 5; ++j) {
    int cidx = lane + 64 * j;
    v[j] = (cidx < CC) ? expf(v[j] - m) : 0.f;
    s += v[j];
  }
#pragma unroll
  for (int off = 32; off >= 1; off >>= 1) s += __shfl_xor(s, off, 64);
  float inv = 1.f / s;
#pragma unroll
  for (int j = 0; j < 5; ++j) {
    int cidx = lane + 64 * j;
    if (cidx < CKP)
      wb[(size_t)d * CKP + cidx] = (cidx < CC) ? f2bf(v[j] * inv) : (unsigned short)0;
  }
}

// ---------------- Kernel 3: out[b,d,t] = sum_c w[d,c] * X[b,c,t] ----------
// Block: one (b, t-tile of 64). All M=272 in-block -> X read exactly once.
// Wave w owns n-subtile w (16 t), accumulates 17 m-tiles in 68 VGPRs.
__global__ __launch_bounds__(256) void gemm_kernel(
    const float* __restrict__ X, const unsigned short* __restrict__ wb,
    float* __restrict__ out) {
  __shared__ unsigned short wlds[MP * LDS_LD];   // 21760 B, [m][k] k-slice
  __shared__ unsigned short xlds[NT * LDS_LD];   // 5120 B,  [t][k] k-slice
  const int bid = blockIdx.x;
  const int b = bid >> 4;
  const int t0 = (bid & 15) * NT;
  const int tid = threadIdx.x;
  const int lane = tid & 63;
  const int wave = tid >> 6;
  const int quad = lane >> 4;
  const int r16 = lane & 15;
  const int kq = quad * 8;

  f32x4 acc[17];
#pragma unroll
  for (int i = 0; i < 17; ++i) acc[i] = (f32x4){0.f, 0.f, 0.f, 0.f};

  const float* Xb = X + (size_t)b * (CC * TT) + t0;
  const int wrow = tid >> 2;       // w-staging: 64 rows x 4 quarters
  const int wq = tid & 3;
  const int tcol = tid & 63;       // X-staging: 64 t x 4 row-groups of 8
  const int pg = tid >> 6;

  for (int kc = 0; kc < 9; ++kc) {
    const int k0 = kc * KK;
    // stage w slice: rows [0,272) x cols [k0,k0+32), 16B per thread per round
#pragma unroll
    for (int it = 0; it < 5; ++it) {
      int rr = wrow + it * 64;
      if (rr < MP) {
        u32x4 wv = *(const u32x4*)(wb + (size_t)rr * CKP + k0 + wq * 8);
        *(u32x4*)(wlds + rr * LDS_LD + wq * 8) = wv;
      }
    }
    // stage X slice transposed+bf16: thread packs 8 k's of one t -> b128 write
    {
      float f[8];
#pragma unroll
      for (int j = 0; j < 8; ++j) {
        int cc_ = k0 + pg * 8 + j;
        f[j] = (cc_ < CC) ? Xb[(size_t)cc_ * TT + tcol] : 0.f;  // K-pad = 0
      }
      unsigned int p[4];
#pragma unroll
      for (int j = 0; j < 4; ++j)
        p[j] = (unsigned int)f2bf(f[2 * j]) | ((unsigned int)f2bf(f[2 * j + 1]) << 16);
      u32x4 xv = {p[0], p[1], p[2], p[3]};
      *(u32x4*)(xlds + tcol * LDS_LD + pg * 8) = xv;
    }
    __syncthreads();
    // B frag: B[k=kq+j][n=lane&15], contiguous k in xlds row
    s16x8 bfrag = *(const s16x8*)(xlds + (wave * 16 + r16) * LDS_LD + kq);
#pragma unroll
    for (int mt = 0; mt < 17; ++mt) {
      // A frag: A[m=lane&15][k=kq+j]
      s16x8 afrag = *(const s16x8*)(wlds + (mt * 16 + r16) * LDS_LD + kq);
      acc[mt] = __builtin_amdgcn_mfma_f32_16x16x32_bf16(afrag, bfrag, acc[mt], 0, 0, 0);
    }
    __syncthreads();
  }

  // epilogue: D[m=quad*4+reg][n=lane&15]
  float* op = out + (size_t)b * (DD * TT) + t0 + wave * 16 + r16;
#pragma unroll
  for (int mt = 0; mt < 17; ++mt) {
#pragma unroll
    for (int r = 0; r < 4; ++r) {
      int drow = mt * 16 + quad * 4 + r;
      if (drow < DD) op[(size_t)drow * TT] = acc[mt][r];
    }
  }
}

extern "C" void kernel_launch(void* const* d_in, const int* in_sizes, int n_in,
                              void* d_out, int out_size, void* d_ws, size_t ws_size,
                              hipStream_t stream) {
  const float* X = (const float*)d_in[0];
  const float* loc = (const float*)d_in[1];
  const float* z_re = (const float*)d_in[2];
  const float* z_im = (const float*)d_in[3];
  float* out = (float*)d_out;

  float* A = (float*)d_ws;                                          // 293,760 B
  unsigned short* wbf = (unsigned short*)((char*)d_ws + 294912);    // 156,672 B

  phaseA_kernel<<<DD, 288, 0, stream>>>(loc, z_re, z_im, A);
  softmax_kernel<<<MP, 64, 0, stream>>>(A, wbf);
  gemm_kernel<<<BB * (TT / NT), 256, 0, stream>>>(X, wbf, out);
}

// Round 2
// 314.456 us; speedup vs baseline: 1.1575x; 1.1575x over previous
//
#include <hip/hip_runtime.h>

#define BB 128
#define CC 272
#define TT 1024
#define DD 270
#define KK 32
#define NKC 9              // K chunks of 32 (C padded to 288)
#define MP 272             // D padded to 17*16
#define NT 256             // t-tile per block (16 waves x 16)
#define WCH (CC * KK)      // ushorts per w chunk = 8704 (272 rows x 64 B)
#define WBYTES (NKC * WCH * 2)   // 156,672 B total w buffer

typedef __attribute__((ext_vector_type(8))) short s16x8;
typedef __attribute__((ext_vector_type(4))) float f32x4;

__device__ __forceinline__ unsigned short f2bf(float f) {
  unsigned int u = __builtin_bit_cast(unsigned int, f);
  u += 0x7fffu + ((u >> 16) & 1u);   // round-to-nearest-even
  return (unsigned short)(u >> 16);
}

// ---------------- Kernel 1: partial A[d][c], 4-way k-split ----------------
// A[d,c] = sum_{k,l} z_re[d,k,l]*cos(2pi(k x_c + l y_c)) + z_im[d,k,l]*sin(...)
// block (d, p): k in [8p, 8p+8). atomicAdd partial into zero-initialized A.
__global__ __launch_bounds__(288) void phaseA_kernel(
    const float* __restrict__ loc, const float* __restrict__ z_re,
    const float* __restrict__ z_im, float* __restrict__ A) {
  const int d = blockIdx.x;
  const int p = blockIdx.y;          // k-part 0..3
  const int c = threadIdx.x;
  if (c >= CC) return;
  const float TWO_PI = 6.28318530717958647692f;
  float x = loc[2 * c], y = loc[2 * c + 1];
  float sx, cx, sy, cyv;
  sincosf(TWO_PI * x, &sx, &cx);
  sincosf(TWO_PI * y, &sy, &cyv);
  float cl[KK], sl[KK];
  cl[0] = 1.f; sl[0] = 0.f;
#pragma unroll
  for (int l = 1; l < KK; ++l) {
    cl[l] = cl[l - 1] * cyv - sl[l - 1] * sy;
    sl[l] = sl[l - 1] * cyv + cl[l - 1] * sy;
  }
  const int k0 = p * 8;
  float sk, ck;
  sincosf(TWO_PI * (float)k0 * x, &sk, &ck);   // exact-ish start of rotation
  const float* zr = z_re + (size_t)d * (KK * KK) + k0 * KK;
  const float* zi = z_im + (size_t)d * (KK * KK) + k0 * KK;
  float acc = 0.f;
  for (int k = 0; k < 8; ++k) {
    float s_rc = 0.f, s_rs = 0.f, s_ic = 0.f, s_is = 0.f;
#pragma unroll
    for (int l = 0; l < KK; ++l) {
      float vr = zr[k * KK + l];   // wave-uniform -> scalar loads
      float vi = zi[k * KK + l];
      s_rc += vr * cl[l];
      s_rs += vr * sl[l];
      s_ic += vi * cl[l];
      s_is += vi * sl[l];
    }
    acc += ck * (s_rc + s_is) + sk * (s_ic - s_rs);
    float nck = ck * cx - sk * sx;
    sk = sk * cx + ck * sx;
    ck = nck;
  }
  atomicAdd(&A[d * CC + c], acc);
}

// ---------------- Kernel 2: row softmax -> bf16 w, swizzled layout --------
// Output layout (ushort index): chunk-major, 64B rows, XOR-swizzled 16B subblocks:
//   idx = kc*WCH + d*32 + ((s ^ (d&3))<<3) + o   where kk = kc*32+ks, s=ks>>3, o=ks&7
// Rows d>=270 and cols kk>=272 are zeros (M/K padding).
__global__ __launch_bounds__(64) void softmax_kernel(
    const float* __restrict__ A, unsigned short* __restrict__ wb) {
  const int d = blockIdx.x;   // 0..271
  const int lane = threadIdx.x;
  const bool live = (d < DD);
  float v[5];
  float inv = 0.f;
  if (live) {
    float m = -3.0e38f;
#pragma unroll
    for (int j = 0; j < 5; ++j) {
      int cidx = lane + 64 * j;
      v[j] = (cidx < CC) ? A[(size_t)d * CC + cidx] : -3.0e38f;
      m = fmaxf(m, v[j]);
    }
#pragma unroll
    for (int off = 32; off >= 1; off >>= 1) m = fmaxf(m, __shfl_xor(m, off, 64));
    float s = 0.f;
#pragma unroll
    for (int j = 0; j < 5; ++j) {
      int cidx = lane + 64 * j;
      v[j] = (cidx < CC) ? expf(v[j] - m) : 0.f;
      s += v[j];
    }
#pragma unroll
    for (int off = 32; off >= 1; off >>= 1) s += __shfl_xor(s, off, 64);
    inv = 1.f / s;
  }
#pragma unroll
  for (int j = 0; j < 5; ++j) {
    int kk = lane + 64 * j;
    if (kk < NKC * KK) {
      unsigned short val = 0;
      if (live && kk < CC) val = f2bf(v[j] * inv);
      int kc = kk >> 5, ks = kk & 31, s = ks >> 3, o = ks & 7;
      wb[(size_t)kc * WCH + d * KK + ((s ^ (d & 3)) << 3) + o] = val;
    }
  }
}

// ---------------- Kernel 3: out[b,d,t] = sum_c w[d,c] * X[b,c,t] ----------
// Block: (b, t-tile of 256), 1024 threads = 16 waves, wave wv owns t-subtile
// [t0+16*wv, +16). Whole w (all 9 chunks) staged ONCE into LDS via
// global_load_lds (flat memcpy, layout pre-swizzled by softmax). K-loop has
// NO barriers: B-frags come straight from global X into registers, one-chunk
// prefetch ahead; A-frags via swizzled (bank-balanced) ds_read_b128.
__global__ __launch_bounds__(1024) void gemm_kernel(
    const float* __restrict__ X, const unsigned short* __restrict__ wb,
    float* __restrict__ out) {
  __shared__ unsigned short wlds[NKC * WCH];   // 156,672 B
  const int bid = blockIdx.x;
  const int b = bid >> 2;
  const int t0 = (bid & 3) * NT;
  const int tid = threadIdx.x;
  const int lane = tid & 63;
  const int wv = tid >> 6;       // 0..15
  const int q = lane >> 4;       // quad 0..3
  const int r16 = lane & 15;

  // ---- stage all of w: 9792 x 16B chunks over 1024 threads (10 rounds) ----
  {
    const char* src = (const char*)wb;
    char* dst = (char*)wlds;
#pragma unroll
    for (int r = 0; r < 10; ++r) {
      int idx = tid + r * 1024;
      if (idx < WBYTES / 16) {   // last round: waves 9..15 fully inactive
        __builtin_amdgcn_global_load_lds(
            (const __attribute__((address_space(1))) unsigned int*)(src + idx * 16),
            (__attribute__((address_space(3))) unsigned int*)(dst + idx * 16),
            16, 0, 0);
      }
    }
  }

  f32x4 acc[17];
#pragma unroll
  for (int i = 0; i < 17; ++i) acc[i] = (f32x4){0.f, 0.f, 0.f, 0.f};

  const float* Xb = X + (size_t)b * (CC * TT) + t0 + wv * 16 + r16;
  const int csub = q * 8;                     // c-offset within chunk for B-frag
  // per-lane byte offset inside a 16-row group of the w chunk (swizzled)
  const int base_l = r16 * 64 + ((q ^ (r16 & 3)) << 4);

  float xf[8];
#pragma unroll
  for (int j = 0; j < 8; ++j) xf[j] = Xb[(size_t)(csub + j) * TT];  // chunk 0

  __syncthreads();   // waits vmcnt(0): w fully in LDS. Last barrier.

  for (int kc = 0; kc < NKC; ++kc) {
    float xn[8];
    if (kc < NKC - 1) {
      const int cbase = (kc + 1) * KK + csub;
#pragma unroll
      for (int j = 0; j < 8; ++j)
        xn[j] = (cbase + j < CC) ? Xb[(size_t)(cbase + j) * TT] : 0.f;
    } else {
#pragma unroll
      for (int j = 0; j < 8; ++j) xn[j] = 0.f;
    }
    union { unsigned int u[4]; s16x8 v; } bf;
#pragma unroll
    for (int j2 = 0; j2 < 4; ++j2)
      bf.u[j2] = (unsigned int)f2bf(xf[2 * j2]) |
                 ((unsigned int)f2bf(xf[2 * j2 + 1]) << 16);
    const char* wchunk = (const char*)wlds + kc * (WCH * 2);
#pragma unroll
    for (int mt = 0; mt < 17; ++mt) {
      s16x8 afrag = *(const s16x8*)(wchunk + mt * 1024 + base_l);
      acc[mt] = __builtin_amdgcn_mfma_f32_16x16x32_bf16(afrag, bf.v, acc[mt], 0, 0, 0);
    }
#pragma unroll
    for (int j = 0; j < 8; ++j) xf[j] = xn[j];
  }

  // epilogue: D[m = q*4 + r][n = r16]
  float* op = out + (size_t)b * (DD * TT) + t0 + wv * 16 + r16;
#pragma unroll
  for (int mt = 0; mt < 17; ++mt) {
#pragma unroll
    for (int r = 0; r < 4; ++r) {
      int drow = mt * 16 + q * 4 + r;
      if (drow < DD) op[(size_t)drow * TT] = acc[mt][r];
    }
  }
}

extern "C" void kernel_launch(void* const* d_in, const int* in_sizes, int n_in,
                              void* d_out, int out_size, void* d_ws, size_t ws_size,
                              hipStream_t stream) {
  const float* X = (const float*)d_in[0];
  const float* loc = (const float*)d_in[1];
  const float* z_re = (const float*)d_in[2];
  const float* z_im = (const float*)d_in[3];
  float* out = (float*)d_out;

  float* A = (float*)d_ws;                                        // 293,760 B
  unsigned short* wbf = (unsigned short*)((char*)d_ws + 294912);  // 156,672 B

  hipMemsetAsync(A, 0, DD * CC * sizeof(float), stream);
  phaseA_kernel<<<dim3(DD, 4), 288, 0, stream>>>(loc, z_re, z_im, A);
  softmax_kernel<<<MP, 64, 0, stream>>>(A, wbf);
  gemm_kernel<<<BB * (TT / NT), 1024, 0, stream>>>(X, wbf, out);
}